// Round 18
// baseline (245.482 us; speedup 1.0000x reference)
//
#include <hip/hip_runtime.h>
#include <hip/hip_bf16.h>

// RNN-T Joiner. N=8 T=512 U=64 J=512 V=500 (padded 512).
// ws: enc_p bf16 [4096,512] | dec_p bf16 [512,512] | wimg bf16 frag-ordered (512KB) | bpad
// prep (273 blocks): conv_wout (128) | enc proj (128) | dec proj (16) | bpad (1)
// joiner: PERSISTENT, grid 256 x 512 thr (1 block/CU), 16 t-tiles/block.
//   Tile: BM=64 (1t x 64u), BN=512, BK=32, 8 waves all-v (wave 64m x 64v, acc[2][2]).
//   Tile j's k-loop streams tile j-1's output from ep LDS (132KB) as NT stores issued
//   AFTER the B-prefetch each kt -> counted vmcnt for B never forces store drains, and
//   stores get a full kt to retire under compute. Only tile 15's drain is exposed.
//   lgkm-only barriers; B-regs 1-kt prefetch; e/d 2-kt prefetch; bias hoisted.

typedef __attribute__((ext_vector_type(4))) float f32x4;
typedef __attribute__((ext_vector_type(16))) float f32x16;
typedef __attribute__((ext_vector_type(4))) short s16x4;
typedef __attribute__((ext_vector_type(8))) short s16x8;
typedef __attribute__((ext_vector_type(4))) unsigned short u16x4;

static __device__ __forceinline__ unsigned short f2bf(float x) {
    union { float f; unsigned u; } v; v.f = x;
    return (unsigned short)((v.u + 0x7FFFu + ((v.u >> 16) & 1u)) >> 16);  // RNE
}

static __device__ __forceinline__ float bf2f(unsigned short u) {
    union { unsigned u; float f; } v; v.u = ((unsigned)u) << 16;
    return v.f;
}

static __device__ __forceinline__ float fast_tanh(float x) {
    float e = __expf(2.0f * x);
    float r = __builtin_amdgcn_rcpf(e + 1.0f);
    return __builtin_fmaf(-2.0f, r, 1.0f);
}

// lgkm-only barrier (R10/R11-verified): orders LDS cross-wave, never drains vmcnt.
static __device__ __forceinline__ void lbar() {
    asm volatile("s_waitcnt lgkmcnt(0)" ::: "memory");
    __builtin_amdgcn_s_barrier();
    __builtin_amdgcn_sched_barrier(0);
}

// 64B-row swizzle: row r, 16B-slot c; byte = r*64 + ((c ^ ((r>>1)&3)) << 4)
static __device__ __forceinline__ unsigned swz64(int r, int c) {
    return (unsigned)(r * 64 + ((c ^ ((r >> 1) & 3)) << 4));
}

// ---------------- projection GEMM body (verified; bf16 output) ----------------
static __device__ void proj_body(
    const float* __restrict__ A, const float* __restrict__ W,
    const float* __restrict__ b, unsigned short* __restrict__ C,
    int mt, int jt, unsigned short* As, unsigned short* Bs)
{
    const int tid = threadIdx.x;
    const int lane = tid & 63, wid = tid >> 6;
    const int wm = wid >> 1, wn = wid & 1;

    f32x4 acc[4][4];
    const f32x4 zero = {0.f, 0.f, 0.f, 0.f};
    #pragma unroll
    for (int i = 0; i < 4; ++i)
        #pragma unroll
        for (int j = 0; j < 4; ++j) acc[i][j] = zero;

    const int c8 = (tid & 7) * 8;
    const int rbase = tid >> 3;

    for (int kt = 0; kt < 8; ++kt) {
        __syncthreads();
        #pragma unroll
        for (int p = 0; p < 4; ++p) {
            int r = p * 32 + rbase;
            int byte = (r * 128 + c8 * 2) ^ ((r & 7) << 4);
            {
                const float* s = A + (size_t)(mt * 128 + r) * 512 + kt * 64 + c8;
                f32x4 v0 = *(const f32x4*)s, v1 = *(const f32x4*)(s + 4);
                s16x8 pk;
                pk[0] = (short)f2bf(v0[0]); pk[1] = (short)f2bf(v0[1]);
                pk[2] = (short)f2bf(v0[2]); pk[3] = (short)f2bf(v0[3]);
                pk[4] = (short)f2bf(v1[0]); pk[5] = (short)f2bf(v1[1]);
                pk[6] = (short)f2bf(v1[2]); pk[7] = (short)f2bf(v1[3]);
                *(s16x8*)((char*)As + byte) = pk;
            }
            {
                const float* s = W + (size_t)(jt * 128 + r) * 512 + kt * 64 + c8;
                f32x4 v0 = *(const f32x4*)s, v1 = *(const f32x4*)(s + 4);
                s16x8 pk;
                pk[0] = (short)f2bf(v0[0]); pk[1] = (short)f2bf(v0[1]);
                pk[2] = (short)f2bf(v0[2]); pk[3] = (short)f2bf(v0[3]);
                pk[4] = (short)f2bf(v1[0]); pk[5] = (short)f2bf(v1[1]);
                pk[6] = (short)f2bf(v1[2]); pk[7] = (short)f2bf(v1[3]);
                *(s16x8*)((char*)Bs + byte) = pk;
            }
        }
        __syncthreads();
        #pragma unroll
        for (int kk = 0; kk < 2; ++kk) {
            s16x8 af[4], bfr[4];
            #pragma unroll
            for (int mi = 0; mi < 4; ++mi) {
                int row = wm * 64 + mi * 16 + (lane & 15);
                int byte = (row * 128 + kk * 64 + ((lane >> 4) * 16)) ^ ((row & 7) << 4);
                af[mi] = *(const s16x8*)((const char*)As + byte);
            }
            #pragma unroll
            for (int ni = 0; ni < 4; ++ni) {
                int row = wn * 64 + ni * 16 + (lane & 15);
                int byte = (row * 128 + kk * 64 + ((lane >> 4) * 16)) ^ ((row & 7) << 4);
                bfr[ni] = *(const s16x8*)((const char*)Bs + byte);
            }
            #pragma unroll
            for (int mi = 0; mi < 4; ++mi)
                #pragma unroll
                for (int ni = 0; ni < 4; ++ni)
                    acc[mi][ni] = __builtin_amdgcn_mfma_f32_16x16x32_bf16(
                        af[mi], bfr[ni], acc[mi][ni], 0, 0, 0);
        }
    }

    #pragma unroll
    for (int ni = 0; ni < 4; ++ni) {
        int col = jt * 128 + wn * 64 + ni * 16 + (lane & 15);
        float bias = b[col];
        #pragma unroll
        for (int mi = 0; mi < 4; ++mi) {
            int row0 = mt * 128 + wm * 64 + mi * 16 + ((lane >> 4) << 2);
            #pragma unroll
            for (int j = 0; j < 4; ++j)
                C[(size_t)(row0 + j) * 512 + col] = f2bf(acc[mi][ni][j] + bias);
        }
    }
}

// ---------------- fused prep: conv_wout | enc proj | dec proj | bpad ----------------
__global__ __launch_bounds__(256) void prep(
    const float* __restrict__ Wout, unsigned short* __restrict__ img,
    const float* __restrict__ encoder_out, const float* __restrict__ W_enc,
    const float* __restrict__ b_enc, unsigned short* __restrict__ enc_p,
    const float* __restrict__ decoder_out, const float* __restrict__ W_dec,
    const float* __restrict__ b_dec, unsigned short* __restrict__ dec_p,
    const float* __restrict__ b_out, float* __restrict__ bpad)
{
    __shared__ unsigned short As[128 * 64];
    __shared__ unsigned short Bs[128 * 64];
    const int b = blockIdx.x;
    if (b < 128) {
        // W_out -> bf16 per-lane MFMA-fragment-ordered image (verified layout):
        // chunk tid = ((kt*16+tile)*2+khalf)*64+lane -> 8 bf16 of
        //   W[v=tile*32+(lane&31)][k=kt*32+khalf*16+(lane>>5)*8 + j], v>=500 -> 0
        int tid = b * 256 + threadIdx.x;
        int lane = tid & 63;
        int khalf = (tid >> 6) & 1;
        int tile = (tid >> 7) & 15;
        int kt = tid >> 11;
        int v = tile * 32 + (lane & 31);
        int k = kt * 32 + khalf * 16 + (lane >> 5) * 8;
        s16x8 pk = {0, 0, 0, 0, 0, 0, 0, 0};
        if (v < 500) {
            const float* s = Wout + (size_t)v * 512 + k;
            f32x4 a = *(const f32x4*)s, c = *(const f32x4*)(s + 4);
            pk[0] = (short)f2bf(a[0]); pk[1] = (short)f2bf(a[1]);
            pk[2] = (short)f2bf(a[2]); pk[3] = (short)f2bf(a[3]);
            pk[4] = (short)f2bf(c[0]); pk[5] = (short)f2bf(c[1]);
            pk[6] = (short)f2bf(c[2]); pk[7] = (short)f2bf(c[3]);
        }
        *(s16x8*)(img + (size_t)tid * 8) = pk;
    } else if (b < 256) {
        int q = b - 128;                       // enc proj: M=4096
        proj_body(encoder_out, W_enc, b_enc, enc_p, q & 31, q >> 5, As, Bs);
    } else if (b < 272) {
        int q = b - 256;                       // dec proj: M=512
        proj_body(decoder_out, W_dec, b_dec, dec_p, q & 3, q >> 2, As, Bs);
    } else {
        int i = threadIdx.x;                   // bpad: 512-padded bias
        bpad[i] = (i < 500) ? b_out[i] : 0.f;
        bpad[i + 256] = (i + 256 < 500) ? b_out[i + 256] : 0.f;
    }
}

// ---------------- fused tanh + vocab GEMM (persistent, store-spread) ----------------
__global__ __launch_bounds__(512, 2) void joiner_main(
    const unsigned short* __restrict__ enc, const unsigned short* __restrict__ dec,
    const unsigned short* __restrict__ Wimg, const float* __restrict__ bout,
    float* __restrict__ out)
{
    __shared__ __align__(16) char raw[8192 + 64 * 516 * 4];   // A dbuf 8KB + ep 132KB
    unsigned short* As0 = (unsigned short*)raw;               // [64 r][32 k] swizzled
    unsigned short* As1 = (unsigned short*)(raw + 4096);
    float* ep = (float*)(raw + 8192);                         // [64][516] f32

    const int bid = blockIdx.x;                 // 0..255
    const int tid = threadIdx.x, lane = tid & 63, wn = tid >> 6;  // 8 waves across V
    const int n = bid >> 5;
    const int t0 = (bid & 31) * 16;

    // A staging coords: thread -> row r = tid>>3 (u 0..63), 8B chunk q (k = q*4..+3)
    const int r = tid >> 3;
    const int q = tid & 7;
    const unsigned short* drow = dec + ((size_t)n * 64 + r) * 512 + q * 4;
    const unsigned abyte = swz64(r, q >> 1) + (q & 1) * 8;
    // B frags: frag-ordered image; wave wn owns v-tiles wn*2+{0,1}
    const char* wbase = (const char*)Wimg + (size_t)wn * 4096 + (size_t)lane * 16;
    const int lr = lane & 31, kg = lane >> 5;
    const int hi4 = kg * 4;

    // bias hoist (once per block; bpad 512-padded, max idx 508+3 < 512)
    f32x4 brg[2][4];
    #pragma unroll
    for (int ni = 0; ni < 2; ++ni)
        #pragma unroll
        for (int qq = 0; qq < 4; ++qq)
            brg[ni][qq] = *(const f32x4*)(bout + wn * 64 + ni * 32 + qq * 8 + hi4);

    f32x16 acc[2][2];

    for (int j = 0; j < 16; ++j) {
        const int t = t0 + j;
        const unsigned short* erow = enc + ((size_t)n * 512 + t) * 512 + q * 4;
        const size_t pslab = (((size_t)n * 512 + (t - 1)) * 64) * 500;  // tile j-1

        #pragma unroll
        for (int i = 0; i < 2; ++i)
            #pragma unroll
            for (int jj = 0; jj < 2; ++jj)
                #pragma unroll
                for (int e = 0; e < 16; ++e) acc[i][jj][e] = 0.f;

        // ---- tile-top: stage A(kt0); prefetch e/d(kt1); load B(kt0) ----
        u16x4 eN, dN;
        s16x8 bc0, bc1, bc2, bc3;
        {
            u16x4 e = *(const u16x4*)erow;
            u16x4 d = *(const u16x4*)drow;
            s16x4 p;
            p[0] = (short)f2bf(fast_tanh(bf2f(e[0]) + bf2f(d[0])));
            p[1] = (short)f2bf(fast_tanh(bf2f(e[1]) + bf2f(d[1])));
            p[2] = (short)f2bf(fast_tanh(bf2f(e[2]) + bf2f(d[2])));
            p[3] = (short)f2bf(fast_tanh(bf2f(e[3]) + bf2f(d[3])));
            *(s16x4*)((char*)As0 + abyte) = p;
            eN = *(const u16x4*)(erow + 32);
            dN = *(const u16x4*)(drow + 32);
            bc0 = *(const s16x8*)(wbase);
            bc1 = *(const s16x8*)(wbase + 1024);
            bc2 = *(const s16x8*)(wbase + 2048);
            bc3 = *(const s16x8*)(wbase + 3072);
        }
        lbar();

        // ---- k-loop: compute tile j; stream tile j-1 from ep (500 chunks/kt) ----
        for (int kt = 0; kt < 16; ++kt) {
            const char* Ac = (char*)((kt & 1) ? As1 : As0);
            char* An = (char*)((kt & 1) ? As0 : As1);

            // 1. stage A(kt+1) from prefetched regs
            if (kt < 15) {
                s16x4 p;
                p[0] = (short)f2bf(fast_tanh(bf2f(eN[0]) + bf2f(dN[0])));
                p[1] = (short)f2bf(fast_tanh(bf2f(eN[1]) + bf2f(dN[1])));
                p[2] = (short)f2bf(fast_tanh(bf2f(eN[2]) + bf2f(dN[2])));
                p[3] = (short)f2bf(fast_tanh(bf2f(eN[3]) + bf2f(dN[3])));
                *(s16x4*)(An + abyte) = p;
            }
            // 2. prefetch e/d(kt+2)
            if (kt < 14) {
                eN = *(const u16x4*)(erow + (kt + 2) * 32);
                dN = *(const u16x4*)(drow + (kt + 2) * 32);
            }
            // 3. prefetch B(kt+1) into regs (BEFORE stores: counted B-wait never
            //    forces a younger store; stores get >=1 kt to drain)
            s16x8 bn0, bn1, bn2, bn3;
            if (kt < 15) {
                const char* g = wbase + (size_t)(kt + 1) * 32768;
                bn0 = *(const s16x8*)(g);
                bn1 = *(const s16x8*)(g + 1024);
                bn2 = *(const s16x8*)(g + 2048);
                bn3 = *(const s16x8*)(g + 3072);
            }
            // 4. A frags + 8 MFMA (swapped operands: D rows = v, cols = m)
            {
                s16x8 a00 = *(const s16x8*)(Ac + swz64(lr, kg));
                s16x8 a10 = *(const s16x8*)(Ac + swz64(32 + lr, kg));
                s16x8 a01 = *(const s16x8*)(Ac + swz64(lr, 2 + kg));
                s16x8 a11 = *(const s16x8*)(Ac + swz64(32 + lr, 2 + kg));
                acc[0][0] = __builtin_amdgcn_mfma_f32_32x32x16_bf16(bc0, a00, acc[0][0], 0, 0, 0);
                acc[0][1] = __builtin_amdgcn_mfma_f32_32x32x16_bf16(bc2, a00, acc[0][1], 0, 0, 0);
                acc[1][0] = __builtin_amdgcn_mfma_f32_32x32x16_bf16(bc0, a10, acc[1][0], 0, 0, 0);
                acc[1][1] = __builtin_amdgcn_mfma_f32_32x32x16_bf16(bc2, a10, acc[1][1], 0, 0, 0);
                acc[0][0] = __builtin_amdgcn_mfma_f32_32x32x16_bf16(bc1, a01, acc[0][0], 0, 0, 0);
                acc[0][1] = __builtin_amdgcn_mfma_f32_32x32x16_bf16(bc3, a01, acc[0][1], 0, 0, 0);
                acc[1][0] = __builtin_amdgcn_mfma_f32_32x32x16_bf16(bc1, a11, acc[1][0], 0, 0, 0);
                acc[1][1] = __builtin_amdgcn_mfma_f32_32x32x16_bf16(bc3, a11, acc[1][1], 0, 0, 0);
            }
            // 5. spread store: 1 contiguous chunk per thread (tile j-1), youngest VMEM
            if (j > 0 && tid < 500) {
                int idx = kt * 500 + tid;               // 8000 chunks total
                int rr = idx / 125;                     // 125 f32x4 per 500-f32 row
                int vi = (idx - rr * 125) * 4;
                f32x4 ov = *(const f32x4*)(ep + rr * 516 + vi);
                __builtin_nontemporal_store(
                    ov, (f32x4*)(out + pslab + (size_t)rr * 500 + vi));
            }
            // 6. lgkm-only barrier
            lbar();
            bc0 = bn0; bc1 = bn1; bc2 = bn2; bc3 = bn3;
        }

        // ---- transpose acc -> ep (with bias); streaming of j-1 finished at kt15 ----
        // acc[mi][ni][reg]: m = mi*32 + lr, v = wn*64 + ni*32 + (reg&3)+8*(reg>>2)+4*kg
        #pragma unroll
        for (int mi = 0; mi < 2; ++mi) {
            #pragma unroll
            for (int ni = 0; ni < 2; ++ni) {
                #pragma unroll
                for (int qq = 0; qq < 4; ++qq) {
                    int v4 = wn * 64 + ni * 32 + qq * 8 + hi4;   // <=508 < 516
                    f32x4 ov;
                    ov[0] = acc[mi][ni][qq * 4 + 0] + brg[ni][qq][0];
                    ov[1] = acc[mi][ni][qq * 4 + 1] + brg[ni][qq][1];
                    ov[2] = acc[mi][ni][qq * 4 + 2] + brg[ni][qq][2];
                    ov[3] = acc[mi][ni][qq * 4 + 3] + brg[ni][qq][3];
                    *(f32x4*)(ep + (mi * 32 + lr) * 516 + v4) = ov;
                }
            }
        }
        lbar();   // ep visible to all waves before next tile's streaming reads
    }

    // ---- final drain: stream tile 15 ----
    {
        const size_t pslab = (((size_t)n * 512 + (t0 + 15)) * 64) * 500;
        #pragma unroll
        for (int kt = 0; kt < 16; ++kt) {
            if (tid < 500) {
                int idx = kt * 500 + tid;
                int rr = idx / 125;
                int vi = (idx - rr * 125) * 4;
                f32x4 ov = *(const f32x4*)(ep + rr * 516 + vi);
                __builtin_nontemporal_store(
                    ov, (f32x4*)(out + pslab + (size_t)rr * 500 + vi));
            }
        }
    }
}

extern "C" void kernel_launch(void* const* d_in, const int* in_sizes, int n_in,
                              void* d_out, int out_size, void* d_ws, size_t ws_size,
                              hipStream_t stream) {
    const float* encoder_out = (const float*)d_in[0];  // [8,512,512]
    const float* decoder_out = (const float*)d_in[1];  // [8,64,512]
    const float* W_enc = (const float*)d_in[2];
    const float* b_enc = (const float*)d_in[3];
    const float* W_dec = (const float*)d_in[4];
    const float* b_dec = (const float*)d_in[5];
    const float* W_out = (const float*)d_in[6];        // [500,512]
    const float* b_out = (const float*)d_in[7];        // [500]
    float* out = (float*)d_out;                        // [8,512,64,500]

    unsigned short* enc_p = (unsigned short*)d_ws;              // 4 MB bf16
    unsigned short* dec_p = enc_p + (size_t)4096 * 512;         // 512 KB bf16
    unsigned short* wimg  = dec_p + (size_t)512 * 512;          // 512 KB bf16
    float* bpad = (float*)(wimg + 262144);                      // 2 KB f32

    prep<<<dim3(273), 256, 0, stream>>>(W_out, wimg,
                                        encoder_out, W_enc, b_enc, enc_p,
                                        decoder_out, W_dec, b_dec, dec_p,
                                        b_out, bpad);
    joiner_main<<<dim3(256), 512, 0, stream>>>(enc_p, dec_p, wimg, bpad, out);
}

// Round 19
// 213.192 us; speedup vs baseline: 1.1515x; 1.1515x over previous
//
#include <hip/hip_runtime.h>
#include <hip/hip_bf16.h>

// RNN-T Joiner. N=8 T=512 U=64 J=512 V=500 (padded 512).  [R14 restored — best: 214.6us]
// ws: enc_p bf16 [4096,512] | dec_p bf16 [512,512] | wimg bf16 frag-ordered (512KB) | bpad
// prep (273 blocks): conv_wout (128) | enc proj (128) | dec proj (16) | bpad (1)
// joiner: 2048 blocks x 512 thr (8 waves). BM=128 (2t x 64u), BN=512, BK=32.
//   Wave tile 128m x 64v (acc[4][2]) -> minimal B L1 traffic. B global->regs, 1-kt
//   prefetch; e/d 2-kt reg prefetch; lgkm-only barriers (never drain vmcnt);
//   LDS-transpose epilogue -> linear NT streams. 1 block/CU.

typedef __attribute__((ext_vector_type(4))) float f32x4;
typedef __attribute__((ext_vector_type(16))) float f32x16;
typedef __attribute__((ext_vector_type(8))) short s16x8;
typedef __attribute__((ext_vector_type(8))) unsigned short u16x8;

static __device__ __forceinline__ unsigned short f2bf(float x) {
    union { float f; unsigned u; } v; v.f = x;
    return (unsigned short)((v.u + 0x7FFFu + ((v.u >> 16) & 1u)) >> 16);  // RNE
}

static __device__ __forceinline__ float bf2f(unsigned short u) {
    union { unsigned u; float f; } v; v.u = ((unsigned)u) << 16;
    return v.f;
}

static __device__ __forceinline__ float fast_tanh(float x) {
    float e = __expf(2.0f * x);
    float r = __builtin_amdgcn_rcpf(e + 1.0f);
    return __builtin_fmaf(-2.0f, r, 1.0f);
}

// lgkm-only barrier (R10/R11-verified): orders LDS cross-wave, never drains vmcnt.
static __device__ __forceinline__ void lbar() {
    asm volatile("s_waitcnt lgkmcnt(0)" ::: "memory");
    __builtin_amdgcn_s_barrier();
    __builtin_amdgcn_sched_barrier(0);
}

// 64B-row swizzle: row r, 16B-slot c; byte = r*64 + ((c ^ ((r>>1)&3)) << 4)
static __device__ __forceinline__ unsigned swz64(int r, int c) {
    return (unsigned)(r * 64 + ((c ^ ((r >> 1) & 3)) << 4));
}

// ---------------- projection GEMM body (verified; bf16 output) ----------------
static __device__ void proj_body(
    const float* __restrict__ A, const float* __restrict__ W,
    const float* __restrict__ b, unsigned short* __restrict__ C,
    int mt, int jt, unsigned short* As, unsigned short* Bs)
{
    const int tid = threadIdx.x;
    const int lane = tid & 63, wid = tid >> 6;
    const int wm = wid >> 1, wn = wid & 1;

    f32x4 acc[4][4];
    const f32x4 zero = {0.f, 0.f, 0.f, 0.f};
    #pragma unroll
    for (int i = 0; i < 4; ++i)
        #pragma unroll
        for (int j = 0; j < 4; ++j) acc[i][j] = zero;

    const int c8 = (tid & 7) * 8;
    const int rbase = tid >> 3;

    for (int kt = 0; kt < 8; ++kt) {
        __syncthreads();
        #pragma unroll
        for (int p = 0; p < 4; ++p) {
            int r = p * 32 + rbase;
            int byte = (r * 128 + c8 * 2) ^ ((r & 7) << 4);
            {
                const float* s = A + (size_t)(mt * 128 + r) * 512 + kt * 64 + c8;
                f32x4 v0 = *(const f32x4*)s, v1 = *(const f32x4*)(s + 4);
                s16x8 pk;
                pk[0] = (short)f2bf(v0[0]); pk[1] = (short)f2bf(v0[1]);
                pk[2] = (short)f2bf(v0[2]); pk[3] = (short)f2bf(v0[3]);
                pk[4] = (short)f2bf(v1[0]); pk[5] = (short)f2bf(v1[1]);
                pk[6] = (short)f2bf(v1[2]); pk[7] = (short)f2bf(v1[3]);
                *(s16x8*)((char*)As + byte) = pk;
            }
            {
                const float* s = W + (size_t)(jt * 128 + r) * 512 + kt * 64 + c8;
                f32x4 v0 = *(const f32x4*)s, v1 = *(const f32x4*)(s + 4);
                s16x8 pk;
                pk[0] = (short)f2bf(v0[0]); pk[1] = (short)f2bf(v0[1]);
                pk[2] = (short)f2bf(v0[2]); pk[3] = (short)f2bf(v0[3]);
                pk[4] = (short)f2bf(v1[0]); pk[5] = (short)f2bf(v1[1]);
                pk[6] = (short)f2bf(v1[2]); pk[7] = (short)f2bf(v1[3]);
                *(s16x8*)((char*)Bs + byte) = pk;
            }
        }
        __syncthreads();
        #pragma unroll
        for (int kk = 0; kk < 2; ++kk) {
            s16x8 af[4], bfr[4];
            #pragma unroll
            for (int mi = 0; mi < 4; ++mi) {
                int row = wm * 64 + mi * 16 + (lane & 15);
                int byte = (row * 128 + kk * 64 + ((lane >> 4) * 16)) ^ ((row & 7) << 4);
                af[mi] = *(const s16x8*)((const char*)As + byte);
            }
            #pragma unroll
            for (int ni = 0; ni < 4; ++ni) {
                int row = wn * 64 + ni * 16 + (lane & 15);
                int byte = (row * 128 + kk * 64 + ((lane >> 4) * 16)) ^ ((row & 7) << 4);
                bfr[ni] = *(const s16x8*)((const char*)Bs + byte);
            }
            #pragma unroll
            for (int mi = 0; mi < 4; ++mi)
                #pragma unroll
                for (int ni = 0; ni < 4; ++ni)
                    acc[mi][ni] = __builtin_amdgcn_mfma_f32_16x16x32_bf16(
                        af[mi], bfr[ni], acc[mi][ni], 0, 0, 0);
        }
    }

    #pragma unroll
    for (int ni = 0; ni < 4; ++ni) {
        int col = jt * 128 + wn * 64 + ni * 16 + (lane & 15);
        float bias = b[col];
        #pragma unroll
        for (int mi = 0; mi < 4; ++mi) {
            int row0 = mt * 128 + wm * 64 + mi * 16 + ((lane >> 4) << 2);
            #pragma unroll
            for (int j = 0; j < 4; ++j)
                C[(size_t)(row0 + j) * 512 + col] = f2bf(acc[mi][ni][j] + bias);
        }
    }
}

// ---------------- fused prep: conv_wout | enc proj | dec proj | bpad ----------------
__global__ __launch_bounds__(256) void prep(
    const float* __restrict__ Wout, unsigned short* __restrict__ img,
    const float* __restrict__ encoder_out, const float* __restrict__ W_enc,
    const float* __restrict__ b_enc, unsigned short* __restrict__ enc_p,
    const float* __restrict__ decoder_out, const float* __restrict__ W_dec,
    const float* __restrict__ b_dec, unsigned short* __restrict__ dec_p,
    const float* __restrict__ b_out, float* __restrict__ bpad)
{
    __shared__ unsigned short As[128 * 64];
    __shared__ unsigned short Bs[128 * 64];
    const int b = blockIdx.x;
    if (b < 128) {
        // W_out -> bf16 per-lane MFMA-fragment-ordered image (verified layout):
        // chunk tid = ((kt*16+tile)*2+khalf)*64+lane -> 8 bf16 of
        //   W[v=tile*32+(lane&31)][k=kt*32+khalf*16+(lane>>5)*8 + j], v>=500 -> 0
        int tid = b * 256 + threadIdx.x;
        int lane = tid & 63;
        int khalf = (tid >> 6) & 1;
        int tile = (tid >> 7) & 15;
        int kt = tid >> 11;
        int v = tile * 32 + (lane & 31);
        int k = kt * 32 + khalf * 16 + (lane >> 5) * 8;
        s16x8 pk = {0, 0, 0, 0, 0, 0, 0, 0};
        if (v < 500) {
            const float* s = Wout + (size_t)v * 512 + k;
            f32x4 a = *(const f32x4*)s, c = *(const f32x4*)(s + 4);
            pk[0] = (short)f2bf(a[0]); pk[1] = (short)f2bf(a[1]);
            pk[2] = (short)f2bf(a[2]); pk[3] = (short)f2bf(a[3]);
            pk[4] = (short)f2bf(c[0]); pk[5] = (short)f2bf(c[1]);
            pk[6] = (short)f2bf(c[2]); pk[7] = (short)f2bf(c[3]);
        }
        *(s16x8*)(img + (size_t)tid * 8) = pk;
    } else if (b < 256) {
        int q = b - 128;                       // enc proj: M=4096
        proj_body(encoder_out, W_enc, b_enc, enc_p, q & 31, q >> 5, As, Bs);
    } else if (b < 272) {
        int q = b - 256;                       // dec proj: M=512
        proj_body(decoder_out, W_dec, b_dec, dec_p, q & 3, q >> 2, As, Bs);
    } else {
        int i = threadIdx.x;                   // bpad: 512-padded bias
        bpad[i] = (i < 500) ? b_out[i] : 0.f;
        bpad[i + 256] = (i + 256 < 500) ? b_out[i + 256] : 0.f;
    }
}

// ---------------- fused tanh + vocab GEMM ----------------
__global__ __launch_bounds__(512, 2) void joiner_main(
    const unsigned short* __restrict__ enc, const unsigned short* __restrict__ dec,
    const unsigned short* __restrict__ Wimg, const float* __restrict__ bout,
    float* __restrict__ out)
{
    __shared__ __align__(16) char raw[66048];         // max(A dbuf 16KB, ep [32][516])
    unsigned short* As0 = (unsigned short*)raw;       // 8 KB [128 r][32 k] swizzled
    unsigned short* As1 = (unsigned short*)(raw + 8192);
    float* ep = (float*)raw;                          // aliases A (used after k-loop)

    const int bid = blockIdx.x;                 // bid = n*256 + tt (tt = t-pair)
    const int tid = threadIdx.x, lane = tid & 63, wn = tid >> 6;  // 8 waves across V
    const int n = bid >> 8, tt = bid & 255;

    f32x16 acc[4][2];
    #pragma unroll
    for (int i = 0; i < 4; ++i)
        #pragma unroll
        for (int j = 0; j < 2; ++j)
            #pragma unroll
            for (int e = 0; e < 16; ++e) acc[i][j][e] = 0.f;

    // A staging: thread -> row r = tid>>2 (0..127: t_local = r>>6, u = r&63),
    //            16B chunk q = tid&3 (k = q*8..+7)
    const int r = tid >> 2;
    const int q = tid & 3;
    const int tl = r >> 6, u = r & 63;
    const unsigned short* erow = enc + ((size_t)n * 512 + tt * 2 + tl) * 512 + q * 8;
    const unsigned short* drow = dec + ((size_t)n * 64 + u) * 512 + q * 8;
    const unsigned abyte = swz64(r, q);
    // B fragments: frag-ordered image; wave wn owns v-tiles wn*2+{0,1}
    // layout: kt*32768 + vtile*2048 + khalf*1024 + lane*16
    const char* wbase = (const char*)Wimg + (size_t)wn * 4096 + (size_t)lane * 16;
    const int lr = lane & 31, kg = lane >> 5;

    // ---- prologue: stage A(kt0); prefetch e/d(kt1); load B(kt0) ----
    s16x8 bc0, bc1, bc2, bc3;
    u16x8 eN, dN;
    {
        u16x8 e = *(const u16x8*)erow;
        u16x8 d = *(const u16x8*)drow;
        s16x8 p;
        #pragma unroll
        for (int i = 0; i < 8; ++i)
            p[i] = (short)f2bf(fast_tanh(bf2f(e[i]) + bf2f(d[i])));
        *(s16x8*)((char*)As0 + abyte) = p;
        eN = *(const u16x8*)(erow + 32);
        dN = *(const u16x8*)(drow + 32);
        bc0 = *(const s16x8*)(wbase);
        bc1 = *(const s16x8*)(wbase + 1024);
        bc2 = *(const s16x8*)(wbase + 2048);
        bc3 = *(const s16x8*)(wbase + 3072);
    }
    lbar();

    #pragma unroll
    for (int kt = 0; kt < 16; ++kt) {
        const char* Ac = (char*)((kt & 1) ? As1 : As0);
        char* An = (char*)((kt & 1) ? As0 : As1);

        // 1. stage A(kt+1) from prefetched e/d regs (tanh on VALU pipe)
        if (kt < 15) {
            s16x8 p;
            #pragma unroll
            for (int i = 0; i < 8; ++i)
                p[i] = (short)f2bf(fast_tanh(bf2f(eN[i]) + bf2f(dN[i])));
            *(s16x8*)(An + abyte) = p;
        }
        // 2. prefetch e/d(kt+2)
        if (kt < 14) {
            eN = *(const u16x8*)(erow + (kt + 2) * 32);
            dN = *(const u16x8*)(drow + (kt + 2) * 32);
        }
        // 3. prefetch B(kt+1) into regs
        s16x8 bn0, bn1, bn2, bn3;
        if (kt < 15) {
            const char* g = wbase + (size_t)(kt + 1) * 32768;
            bn0 = *(const s16x8*)(g);
            bn1 = *(const s16x8*)(g + 1024);
            bn2 = *(const s16x8*)(g + 2048);
            bn3 = *(const s16x8*)(g + 3072);
        }
        // 4. kh0: A frags (4 m-subtiles) + 8 MFMAs
        {
            s16x8 a0 = *(const s16x8*)(Ac + swz64(lr, kg));
            s16x8 a1 = *(const s16x8*)(Ac + swz64(32 + lr, kg));
            s16x8 a2 = *(const s16x8*)(Ac + swz64(64 + lr, kg));
            s16x8 a3 = *(const s16x8*)(Ac + swz64(96 + lr, kg));
            acc[0][0] = __builtin_amdgcn_mfma_f32_32x32x16_bf16(bc0, a0, acc[0][0], 0, 0, 0);
            acc[0][1] = __builtin_amdgcn_mfma_f32_32x32x16_bf16(bc2, a0, acc[0][1], 0, 0, 0);
            acc[1][0] = __builtin_amdgcn_mfma_f32_32x32x16_bf16(bc0, a1, acc[1][0], 0, 0, 0);
            acc[1][1] = __builtin_amdgcn_mfma_f32_32x32x16_bf16(bc2, a1, acc[1][1], 0, 0, 0);
            acc[2][0] = __builtin_amdgcn_mfma_f32_32x32x16_bf16(bc0, a2, acc[2][0], 0, 0, 0);
            acc[2][1] = __builtin_amdgcn_mfma_f32_32x32x16_bf16(bc2, a2, acc[2][1], 0, 0, 0);
            acc[3][0] = __builtin_amdgcn_mfma_f32_32x32x16_bf16(bc0, a3, acc[3][0], 0, 0, 0);
            acc[3][1] = __builtin_amdgcn_mfma_f32_32x32x16_bf16(bc2, a3, acc[3][1], 0, 0, 0);
        }
        // 5. kh1
        {
            s16x8 a0 = *(const s16x8*)(Ac + swz64(lr, 2 + kg));
            s16x8 a1 = *(const s16x8*)(Ac + swz64(32 + lr, 2 + kg));
            s16x8 a2 = *(const s16x8*)(Ac + swz64(64 + lr, 2 + kg));
            s16x8 a3 = *(const s16x8*)(Ac + swz64(96 + lr, 2 + kg));
            acc[0][0] = __builtin_amdgcn_mfma_f32_32x32x16_bf16(bc1, a0, acc[0][0], 0, 0, 0);
            acc[0][1] = __builtin_amdgcn_mfma_f32_32x32x16_bf16(bc3, a0, acc[0][1], 0, 0, 0);
            acc[1][0] = __builtin_amdgcn_mfma_f32_32x32x16_bf16(bc1, a1, acc[1][0], 0, 0, 0);
            acc[1][1] = __builtin_amdgcn_mfma_f32_32x32x16_bf16(bc3, a1, acc[1][1], 0, 0, 0);
            acc[2][0] = __builtin_amdgcn_mfma_f32_32x32x16_bf16(bc1, a2, acc[2][0], 0, 0, 0);
            acc[2][1] = __builtin_amdgcn_mfma_f32_32x32x16_bf16(bc3, a2, acc[2][1], 0, 0, 0);
            acc[3][0] = __builtin_amdgcn_mfma_f32_32x32x16_bf16(bc1, a3, acc[3][0], 0, 0, 0);
            acc[3][1] = __builtin_amdgcn_mfma_f32_32x32x16_bf16(bc3, a3, acc[3][1], 0, 0, 0);
        }
        // 6. lgkm-only barrier; B/ed prefetch stays in flight
        lbar();
        bc0 = bn0; bc1 = bn1; bc2 = bn2; bc3 = bn3;
    }

    // ---- epilogue: 4 rounds of 32 rows (round o = acc[o]); LDS transpose ->
    //      linear NT streams. acc[mi][ni][reg]: m = mi*32 + lr,
    //      v = wn*64 + ni*32 + (reg&3) + 8*(reg>>2) + 4*kg
    const int hi4 = kg * 4;
    #pragma unroll
    for (int o = 0; o < 4; ++o) {
        if (o) lbar();                    // round 0 covered by k-loop's final lbar
        {
            #pragma unroll
            for (int ni = 0; ni < 2; ++ni) {
                #pragma unroll
                for (int qq = 0; qq < 4; ++qq) {
                    int v4 = wn * 64 + ni * 32 + qq * 8 + hi4;
                    if (v4 < 500) {
                        f32x4 b = *(const f32x4*)(bout + v4);   // bout 512-padded
                        f32x4 ov;
                        ov[0] = acc[o][ni][qq * 4 + 0] + b[0];
                        ov[1] = acc[o][ni][qq * 4 + 1] + b[1];
                        ov[2] = acc[o][ni][qq * 4 + 2] + b[2];
                        ov[3] = acc[o][ni][qq * 4 + 3] + b[3];
                        *(f32x4*)(ep + lr * 516 + v4) = ov;
                    }
                }
            }
        }
        lbar();
        // rows o*32..o*32+31 of the 128-row tile: t_local = o>>1, u0 = (o&1)*32
        const size_t base =
            (((size_t)n * 512 + tt * 2 + (o >> 1)) * 64 + (o & 1) * 32) * 500;
        #pragma unroll
        for (int i = 0; i < 8; ++i) {
            int idx = i * 512 + tid;                    // f32x4 chunk, 4000 total
            if (idx < 4000) {
                int rr = idx / 125;
                int vi = (idx - rr * 125) * 4;
                f32x4 ov = *(const f32x4*)(ep + rr * 516 + vi);
                __builtin_nontemporal_store(ov, (f32x4*)(out + base + (size_t)idx * 4));
            }
        }
    }
}

extern "C" void kernel_launch(void* const* d_in, const int* in_sizes, int n_in,
                              void* d_out, int out_size, void* d_ws, size_t ws_size,
                              hipStream_t stream) {
    const float* encoder_out = (const float*)d_in[0];  // [8,512,512]
    const float* decoder_out = (const float*)d_in[1];  // [8,64,512]
    const float* W_enc = (const float*)d_in[2];
    const float* b_enc = (const float*)d_in[3];
    const float* W_dec = (const float*)d_in[4];
    const float* b_dec = (const float*)d_in[5];
    const float* W_out = (const float*)d_in[6];        // [500,512]
    const float* b_out = (const float*)d_in[7];        // [500]
    float* out = (float*)d_out;                        // [8,512,64,500]

    unsigned short* enc_p = (unsigned short*)d_ws;              // 4 MB bf16
    unsigned short* dec_p = enc_p + (size_t)4096 * 512;         // 512 KB bf16
    unsigned short* wimg  = dec_p + (size_t)512 * 512;          // 512 KB bf16
    float* bpad = (float*)(wimg + 262144);                      // 2 KB f32

    prep<<<dim3(273), 256, 0, stream>>>(W_out, wimg,
                                        encoder_out, W_enc, b_enc, enc_p,
                                        decoder_out, W_dec, b_dec, dec_p,
                                        b_out, bpad);
    joiner_main<<<dim3(2048), 512, 0, stream>>>(enc_p, dec_p, wimg, bpad, out);
}